// Round 16
// baseline (149.643 us; speedup 1.0000x reference)
//
#include <hip/hip_runtime.h>

#define NBLK 256

typedef float f2 __attribute__((ext_vector_type(2)));   // VGPR pair -> VOP3P v_pk_* f32
typedef float f4 __attribute__((ext_vector_type(4)));

static __device__ __forceinline__ f2 pk_fma(f2 a, f2 b, f2 c) {
#if __has_builtin(__builtin_elementwise_fma)
    return __builtin_elementwise_fma(a, b, c);
#else
    f2 r; r.x = fmaf(a.x, b.x, c.x); r.y = fmaf(a.y, b.y, c.y); return r;
#endif
}

// packed tanh(z) and 1-tanh^2: tanh = 1 - 2/(exp2(2*log2e*z)+1). abs err ~3e-7.
__device__ __forceinline__ void tanh2(const f2 z, f2& th, f2& om) {
    const f2 zz = z * 2.88539008f;
    f2 s;
    s.x = __builtin_amdgcn_rcpf(__builtin_amdgcn_exp2f(zz.x) + 1.0f);
    s.y = __builtin_amdgcn_rcpf(__builtin_amdgcn_exp2f(zz.y) + 1.0f);
    th = 1.0f - 2.0f * s;
    om = 1.0f - th * th;
}

// LDS float-index layout (all 16B-aligned where read as f4):
#define OFF_W234 0       // W2,W3,W4 row-major, 400 each (rows 80B -> f4-aligned)
#define OFF_B234 1200    // b2,b3,b4 (20 each)
#define OFF_W1   1260    // 20
#define OFF_B1   1280    // 20
#define OFF_WOT  1300    // Wo transposed [3][20] (rows 80B -> f4-aligned)
#define OFF_BO   1360    // 3
#define SM_SIZE  1364

__global__ __launch_bounds__(NBLK) void pinn_kernel(
    const float* __restrict__ T,
    const float* __restrict__ W1, const float* __restrict__ b1,
    const float* __restrict__ W2, const float* __restrict__ b2,
    const float* __restrict__ W3, const float* __restrict__ b3,
    const float* __restrict__ W4, const float* __restrict__ b4,
    const float* __restrict__ Wo, const float* __restrict__ bo,
    const float* __restrict__ C1, const float* __restrict__ C2, const float* __restrict__ C3,
    float* __restrict__ out, int n)
{
    // ALL weights in LDS: zero SMEM in the hot path. DS returns in-order ->
    // partial lgkmcnt(N) waits pipeline (SMEM is OOO -> full drains = R7..R15's
    // ~22us idle). All reads: one zero base + imm offsets, no per-read VALU.
    // LDS pipe ~32us/CU hides under the ~55us VALU shadow. Broadcast reads: no conflicts.
    __shared__ __align__(16) float sm[SM_SIZE];

    {
        const int u = threadIdx.x;
        for (int idx = u; idx < 400; idx += NBLK) {
            sm[OFF_W234 +       idx] = W2[idx];
            sm[OFF_W234 + 400 + idx] = W3[idx];
            sm[OFF_W234 + 800 + idx] = W4[idx];
        }
        if (u < 20) {
            sm[OFF_B234 +      u] = b2[u];
            sm[OFF_B234 + 20 + u] = b3[u];
            sm[OFF_B234 + 40 + u] = b4[u];
            sm[OFF_W1 + u] = W1[u];
            sm[OFF_B1 + u] = b1[u];
        }
        if (u < 60) sm[OFF_WOT + (u % 3) * 20 + (u / 3)] = Wo[u];  // [j][k] = Wo[k*3+j]
        if (u < 3)  sm[OFF_BO + u] = bo[u];
    }
    __syncthreads();

    const int i0 = blockIdx.x * NBLK + threadIdx.x;
    const int i  = (i0 < n) ? i0 : (n - 1);        // clamp load; store guarded below
    const float t = T[i];

    f2 H[10], D[10];
    const f2 t2 = {t, t};

    // ---- layer 1: z = t*W1 + b1, dz = W1 (tangent dt = 1) ----
#pragma unroll
    for (int jj = 0; jj < 10; ++jj) {
        const f2 w = *reinterpret_cast<const f2*>(sm + OFF_W1 + 2 * jj);
        const f2 b = *reinterpret_cast<const f2*>(sm + OFF_B1 + 2 * jj);
        f2 th, om;
        tanh2(pk_fma(t2, w, b), th, om);
        H[jj] = th;
        D[jj] = om * w;
    }

    // ---- layers 2..4: k-outer / q-inner; per (k,q) one ds_read_b128 + 4 pk_fma ----
#define LAYER(LIDX) do {                                                        \
        f2 A[10], DD[10];                                                       \
        _Pragma("unroll")                                                       \
        for (int jj = 0; jj < 10; ++jj) {                                       \
            A[jj]  = *reinterpret_cast<const f2*>(sm + OFF_B234 + LIDX*20 + 2*jj); \
            DD[jj] = (f2){0.0f, 0.0f};                                          \
        }                                                                       \
        _Pragma("unroll")                                                       \
        for (int k = 0; k < 20; ++k) {                                          \
            const float hk = (k & 1) ? H[k >> 1].y : H[k >> 1].x;               \
            const float dk = (k & 1) ? D[k >> 1].y : D[k >> 1].x;               \
            const f2 hk2 = {hk, hk};                                            \
            const f2 dk2 = {dk, dk};                                            \
            _Pragma("unroll")                                                   \
            for (int q = 0; q < 5; ++q) {                                       \
                const f4 w4 = *reinterpret_cast<const f4*>(                     \
                    sm + OFF_W234 + LIDX*400 + k*20 + 4*q);                     \
                const f2 wa = {w4.x, w4.y}, wb = {w4.z, w4.w};                  \
                A[2*q]    = pk_fma(hk2, wa, A[2*q]);                            \
                A[2*q+1]  = pk_fma(hk2, wb, A[2*q+1]);                          \
                DD[2*q]   = pk_fma(dk2, wa, DD[2*q]);                           \
                DD[2*q+1] = pk_fma(dk2, wb, DD[2*q+1]);                         \
            }                                                                   \
        }                                                                       \
        _Pragma("unroll")                                                       \
        for (int jj = 0; jj < 10; ++jj) {                                       \
            f2 th, om;                                                          \
            tanh2(A[jj], th, om);                                               \
            H[jj] = th;                                                         \
            D[jj] = om * DD[jj];                                                \
        }                                                                       \
    } while (0)

    LAYER(0);
    LAYER(1);
    LAYER(2);
#undef LAYER

    // ---- output layer via transposed Wo: o_j = sum_k h[k]*WoT[j][k] (f2 over k-pairs) ----
    float o[3], g[3];
#pragma unroll
    for (int j = 0; j < 3; ++j) {
        f2 oa = {0.0f, 0.0f}, ga = {0.0f, 0.0f};
#pragma unroll
        for (int q = 0; q < 5; ++q) {
            const f4 w4 = *reinterpret_cast<const f4*>(sm + OFF_WOT + j * 20 + 4 * q);
            const f2 wa = {w4.x, w4.y}, wb = {w4.z, w4.w};
            oa = pk_fma(H[2*q],     wa, oa);
            ga = pk_fma(D[2*q],     wa, ga);
            oa = pk_fma(H[2*q + 1], wb, oa);
            ga = pk_fma(D[2*q + 1], wb, ga);
        }
        o[j] = oa.x + oa.y + sm[OFF_BO + j];
        g[j] = ga.x + ga.y;
    }

    const float x = o[0], y = o[1], zz = o[2];
    const float c1 = C1[0], c2 = C2[0], c3 = C3[0];
    const float fx = g[0] - c1 * (y - x);
    const float fy = g[1] - x * (c2 - zz) + y;
    const float fz = g[2] - x * y + c3 * zz;

    if (i0 < n) {
        // 24*i bytes is 8B-aligned -> three float2 stores
        float2* po = reinterpret_cast<float2*>(out + (size_t)i0 * 6);
        po[0] = make_float2(x,  y);
        po[1] = make_float2(zz, fx);
        po[2] = make_float2(fy, fz);
    }
}

extern "C" void kernel_launch(void* const* d_in, const int* in_sizes, int n_in,
                              void* d_out, int out_size, void* d_ws, size_t ws_size,
                              hipStream_t stream) {
    const float* T  = (const float*)d_in[0];
    const float* W1 = (const float*)d_in[1];
    const float* b1 = (const float*)d_in[2];
    const float* W2 = (const float*)d_in[3];
    const float* b2 = (const float*)d_in[4];
    const float* W3 = (const float*)d_in[5];
    const float* b3 = (const float*)d_in[6];
    const float* W4 = (const float*)d_in[7];
    const float* b4 = (const float*)d_in[8];
    const float* Wo = (const float*)d_in[9];
    const float* bo = (const float*)d_in[10];
    const float* C1 = (const float*)d_in[11];
    const float* C2 = (const float*)d_in[12];
    const float* C3 = (const float*)d_in[13];
    float* out = (float*)d_out;

    const int n = in_sizes[0];
    const int blocks = (n + NBLK - 1) / NBLK;
    pinn_kernel<<<blocks, NBLK, 0, stream>>>(T, W1, b1, W2, b2, W3, b3, W4, b4,
                                             Wo, bo, C1, C2, C3, out, n);
}